// Round 1
// baseline (35.361 us; speedup 1.0000x reference)
//
#include <hip/hip_runtime.h>

// SurvPLE (Cox partial likelihood) loss, n = 16384.
// loss = -mean_i( (theta_i - log( sum_j exp(theta_j)*[T_j >= T_i] )) * E_i )
// T = |y|, E = (y > 0), theta = y_hat.
//
// K1: brute-force O(n^2) risk sums, i-split x j-split, LDS-tiled (float2),
//     IPT accumulators per thread to amortize LDS reads.
// K2: per-i finalize (sum j-chunk partials, theta - log, mask by E) + block reduce.
// K3: deterministic final sum (single thread over 64 block partials).

constexpr int BLOCK = 256;
constexpr int IPT   = 4;              // i's per thread
constexpr int ICH   = BLOCK * IPT;    // 1024 i per block
constexpr int JC    = 32;             // j-split factor
constexpr int TILE  = 512;            // j-tile in LDS (float2 -> 4 KB)

__global__ __launch_bounds__(BLOCK) void k_risksum(
    const float* __restrict__ y, const float* __restrict__ yhat,
    float* __restrict__ rs_part, int n, int ibs)
{
    __shared__ float2 sTW[TILE];

    const int ib  = blockIdx.x % ibs;   // i-chunk
    const int jc  = blockIdx.x / ibs;   // j-chunk
    const int tid = threadIdx.x;
    const int ibase = ib * ICH;
    const int chunk = n / JC;
    const int jbase = jc * chunk;

    float Ti[IPT];
    float rs[IPT];
#pragma unroll
    for (int k = 0; k < IPT; ++k) {
        Ti[k] = fabsf(y[ibase + k * BLOCK + tid]);
        rs[k] = 0.0f;
    }

    for (int j0 = jbase; j0 < jbase + chunk; j0 += TILE) {
        __syncthreads();
        for (int t = tid; t < TILE; t += BLOCK) {
            const int j = j0 + t;
            sTW[t] = make_float2(fabsf(y[j]), expf(yhat[j]));
        }
        __syncthreads();
#pragma unroll 8
        for (int t = 0; t < TILE; ++t) {
            const float2 tw = sTW[t];
#pragma unroll
            for (int k = 0; k < IPT; ++k)
                rs[k] += (tw.x >= Ti[k]) ? tw.y : 0.0f;
        }
    }

#pragma unroll
    for (int k = 0; k < IPT; ++k)
        rs_part[(size_t)jc * n + ibase + k * BLOCK + tid] = rs[k];
}

__global__ __launch_bounds__(BLOCK) void k_finalize(
    const float* __restrict__ y, const float* __restrict__ yhat,
    const float* __restrict__ rs_part, float* __restrict__ bsum, int n)
{
    const int i = blockIdx.x * BLOCK + threadIdx.x;

    float rs = 0.0f;
#pragma unroll
    for (int jc = 0; jc < JC; ++jc)
        rs += rs_part[(size_t)jc * n + i];

    const float yi = y[i];
    float p = (yi > 0.0f) ? (yhat[i] - logf(rs)) : 0.0f;

    // wave reduce (64 lanes) then cross-wave via LDS
#pragma unroll
    for (int off = 32; off > 0; off >>= 1)
        p += __shfl_down(p, off, 64);

    __shared__ float sred[BLOCK / 64];
    const int wid  = threadIdx.x >> 6;
    const int lane = threadIdx.x & 63;
    if (lane == 0) sred[wid] = p;
    __syncthreads();
    if (threadIdx.x == 0) {
        float s = 0.0f;
#pragma unroll
        for (int w = 0; w < BLOCK / 64; ++w) s += sred[w];
        bsum[blockIdx.x] = s;
    }
}

__global__ void k_out(const float* __restrict__ bsum, float* __restrict__ out,
                      int n, int nb)
{
    if (threadIdx.x == 0 && blockIdx.x == 0) {
        float s = 0.0f;
        for (int b = 0; b < nb; ++b) s += bsum[b];   // deterministic order
        out[0] = -s / (float)n;
    }
}

extern "C" void kernel_launch(void* const* d_in, const int* in_sizes, int n_in,
                              void* d_out, int out_size, void* d_ws, size_t ws_size,
                              hipStream_t stream) {
    const float* y    = (const float*)d_in[0];
    const float* yhat = (const float*)d_in[1];
    float* out        = (float*)d_out;
    const int n       = in_sizes[0];        // 16384

    float* rs_part = (float*)d_ws;                     // JC * n floats
    float* bsum    = rs_part + (size_t)JC * n;         // n/BLOCK floats

    const int ibs = n / ICH;                           // 16 i-chunks
    const int nb  = n / BLOCK;                         // 64 finalize blocks

    k_risksum<<<dim3(ibs * JC), dim3(BLOCK), 0, stream>>>(y, yhat, rs_part, n, ibs);
    k_finalize<<<dim3(nb), dim3(BLOCK), 0, stream>>>(y, yhat, rs_part, bsum, n);
    k_out<<<dim3(1), dim3(64), 0, stream>>>(bsum, out, n, nb);
}